// Round 4
// baseline (764.977 us; speedup 1.0000x reference)
//
#include <hip/hip_runtime.h>
#include <hip/hip_bf16.h>

typedef unsigned short u16;
typedef unsigned int u32;
typedef unsigned long long u64;
typedef __attribute__((ext_vector_type(8))) short short8v;
typedef __attribute__((ext_vector_type(4))) float f32x4;

#define MFMA16(a,b,c) __builtin_amdgcn_mfma_f32_16x16x32_bf16(a,b,c,0,0,0)
#define NEGV -1e9f
#define MOFF 20.0f

__device__ __forceinline__ float b2f(u16 u){ return __uint_as_float(((u32)u)<<16); }
__device__ __forceinline__ u16 f2b(float f){
  __hip_bfloat16 h = __float2bfloat16(f);   // RNE, compiler lowers to cvt_pk
  return __builtin_bit_cast(u16, h);
}
__device__ __forceinline__ u32 pk2(float a, float b){
  return (u32)f2b(a) | ((u32)f2b(b) << 16);
}

// ---------------------------------------------------------------------------
// Transpose+convert the 4 weight matrices: Wt[n][k] (bf16) from W[k][n] (f32).
// grid (12,12,4), block 256, 64x64 tiles.
// ---------------------------------------------------------------------------
__global__ __launch_bounds__(256) void wcvt(
    const float* __restrict__ W0, const float* __restrict__ W1,
    const float* __restrict__ W2, const float* __restrict__ W3,
    u16* __restrict__ Wt)
{
  __shared__ u16 Tl[64*72];
  const int z = blockIdx.z;
  const float* W = z==0 ? W0 : z==1 ? W1 : z==2 ? W2 : W3;
  u16* Wo = Wt + (size_t)z * 768 * 768;
  const int t = threadIdx.x;
  const int n0 = blockIdx.x*64, k0 = blockIdx.y*64;
  const int r = t>>2, cs = (t&3)*16;
  {
    const float* src = W + (size_t)(k0+r)*768 + n0 + cs;
    float4 f0 = ((const float4*)src)[0];
    float4 f1 = ((const float4*)src)[1];
    float4 f2 = ((const float4*)src)[2];
    float4 f3 = ((const float4*)src)[3];
    uint4 o0 = { pk2(f0.x,f0.y), pk2(f0.z,f0.w), pk2(f1.x,f1.y), pk2(f1.z,f1.w) };
    uint4 o1 = { pk2(f2.x,f2.y), pk2(f2.z,f2.w), pk2(f3.x,f3.y), pk2(f3.z,f3.w) };
    *(uint4*)&Tl[r*72 + cs]     = o0;
    *(uint4*)&Tl[r*72 + cs + 8] = o1;
  }
  __syncthreads();
  {
    // write row n = n0+r, cols k = k0+cs..+15 ; Wt[n][k] = Tl[k-k0][n-n0]
    u16 v[16];
    #pragma unroll
    for (int j = 0; j < 16; ++j) v[j] = Tl[(cs+j)*72 + r];
    uint4 o0, o1;
    u32* p0 = (u32*)&o0; u32* p1 = (u32*)&o1;
    #pragma unroll
    for (int j = 0; j < 4; ++j) p0[j] = (u32)v[2*j] | ((u32)v[2*j+1]<<16);
    #pragma unroll
    for (int j = 0; j < 4; ++j) p1[j] = (u32)v[8+2*j] | ((u32)v[8+2*j+1]<<16);
    *(uint4*)(Wo + (size_t)(n0+r)*768 + k0 + cs)     = o0;
    *(uint4*)(Wo + (size_t)(n0+r)*768 + k0 + cs + 8) = o1;
  }
}

// ---------------------------------------------------------------------------
// MFMA GEMM: C = A(8192x768) @ Wt^T + bias, Wt is [n][k] bf16.
// Tile 128x128, 4 waves (2x2), wave-tile 64x64, K-step 32.
// ABF16: A bf16 else fp32 (converted in staging).
// OMODE 0: fp32 row-major; 1: bf16 head-split [bh][l][64];
//       2: bf16 head-split transposed [bh][d][1024] (V).
// 1D grid 384, XCD-swizzled: xcd=id&7, r=id>>3, n=r%6, m=(r/6)*8+xcd.
// ---------------------------------------------------------------------------
template<int ABF16, int OMODE>
__global__ __launch_bounds__(256) void gemm_mfma(
    const void* __restrict__ Av, const u16* __restrict__ Wt,
    const float* __restrict__ bias, float* __restrict__ outF,
    u16* __restrict__ outB)
{
  __shared__ u16 Al[128*40];
  __shared__ u16 Bl[128*40];
  const int t = threadIdx.x;
  const int lane = t & 63, wid = t >> 6;
  const int l15 = lane & 15, lg = lane >> 4;
  const int wm = wid >> 1, wn = wid & 1;

  const int id = blockIdx.x;
  const int xcd = id & 7, rr = id >> 3;
  const int nb = rr % 6, mb = (rr / 6) * 8 + xcd;
  const int n0 = nb * 128, m0 = mb * 128;

  f32x4 acc[4][4];
  #pragma unroll
  for (int mi = 0; mi < 4; ++mi)
    #pragma unroll
    for (int ni = 0; ni < 4; ++ni)
      acc[mi][ni] = (f32x4){0.f,0.f,0.f,0.f};

  const int arow = t >> 1, aseg = (t & 1) * 16;

  for (int k0 = 0; k0 < 768; k0 += 32) {
    __syncthreads();
    if (ABF16) {
      const u16* A = (const u16*)Av + (size_t)(m0 + arow) * 768 + k0 + aseg;
      uint4 a0 = ((const uint4*)A)[0];
      uint4 a1 = ((const uint4*)A)[1];
      *(uint4*)&Al[arow*40 + aseg]     = a0;
      *(uint4*)&Al[arow*40 + aseg + 8] = a1;
    } else {
      const float* A = (const float*)Av + (size_t)(m0 + arow) * 768 + k0 + aseg;
      float4 f0 = ((const float4*)A)[0];
      float4 f1 = ((const float4*)A)[1];
      float4 f2 = ((const float4*)A)[2];
      float4 f3 = ((const float4*)A)[3];
      uint4 o0 = { pk2(f0.x,f0.y), pk2(f0.z,f0.w), pk2(f1.x,f1.y), pk2(f1.z,f1.w) };
      uint4 o1 = { pk2(f2.x,f2.y), pk2(f2.z,f2.w), pk2(f3.x,f3.y), pk2(f3.z,f3.w) };
      *(uint4*)&Al[arow*40 + aseg]     = o0;
      *(uint4*)&Al[arow*40 + aseg + 8] = o1;
    }
    {
      const u16* B = Wt + (size_t)(n0 + arow) * 768 + k0 + aseg;
      uint4 b0 = ((const uint4*)B)[0];
      uint4 b1 = ((const uint4*)B)[1];
      *(uint4*)&Bl[arow*40 + aseg]     = b0;
      *(uint4*)&Bl[arow*40 + aseg + 8] = b1;
    }
    __syncthreads();
    short8v af[4], bf[4];
    #pragma unroll
    for (int mi = 0; mi < 4; ++mi)
      af[mi] = *(const short8v*)&Al[(wm*64 + mi*16 + l15)*40 + lg*8];
    #pragma unroll
    for (int ni = 0; ni < 4; ++ni)
      bf[ni] = *(const short8v*)&Bl[(wn*64 + ni*16 + l15)*40 + lg*8];
    #pragma unroll
    for (int mi = 0; mi < 4; ++mi)
      #pragma unroll
      for (int ni = 0; ni < 4; ++ni)
        acc[mi][ni] = MFMA16(af[mi], bf[ni], acc[mi][ni]);
  }

  #pragma unroll
  for (int mi = 0; mi < 4; ++mi)
  #pragma unroll
  for (int ni = 0; ni < 4; ++ni) {
    const int col  = n0 + wn*64 + ni*16 + l15;
    const int row0 = m0 + wm*64 + mi*16 + lg*4;
    const float bv = bias[col];
    if (OMODE == 0) {
      #pragma unroll
      for (int r = 0; r < 4; ++r)
        outF[(size_t)(row0 + r) * 768 + col] = acc[mi][ni][r] + bv;
    } else if (OMODE == 1) {
      const int h = col >> 6, d = col & 63;
      #pragma unroll
      for (int r = 0; r < 4; ++r) {
        const int row = row0 + r;
        const int bb = row >> 10, l = row & 1023;
        outB[(((size_t)(bb*12 + h))*1024 + l)*64 + d] = f2b(acc[mi][ni][r] + bv);
      }
    } else {
      const int h = col >> 6, d = col & 63;
      const int bb = row0 >> 10, l0 = row0 & 1023;
      ushort4 pk;
      pk.x = f2b(acc[mi][ni][0] + bv);
      pk.y = f2b(acc[mi][ni][1] + bv);
      pk.z = f2b(acc[mi][ni][2] + bv);
      pk.w = f2b(acc[mi][ni][3] + bv);
      *(ushort4*)(outB + (((size_t)(bb*12 + h))*64 + d)*1024 + l0) = pk;
    }
  }
}

// ---------------------------------------------------------------------------
// Fused attention, fixed-offset softmax (M=20), directional tile skipping,
// degenerate-row (L==0) exact slow path.
// Block = (bh, 64 q-rows), wave = 16 q-rows. XCD swizzle: bh&7 = xcd.
// ---------------------------------------------------------------------------
__device__ __forceinline__ void side_unit(
    const f32x4 (&sv)[4], f32x4 (&acc)[4], float (&L)[4],
    int side, bool diag, int kt, int rowg0, int l15, int lg,
    u16* Pw, const u16* Vl)
{
  float p[4][4];
  #pragma unroll
  for (int ni = 0; ni < 4; ++ni) {
    #pragma unroll
    for (int r = 0; r < 4; ++r) {
      float arg = sv[ni][r] - MOFF;
      if (diag) {
        const int colg = kt*64 + ni*16 + l15;
        const int rowg = rowg0 + lg*4 + r;
        const bool msk = side ? (colg > rowg) : (colg < rowg);
        if (msk) arg = sv[ni][r] + NEGV - MOFF;
      }
      const float pe = __expf(arg);
      p[ni][r] = pe;
      L[r] += pe;
    }
  }
  // swizzled store: group ^= row's lg  (bank-conflict-free)
  #pragma unroll
  for (int ni = 0; ni < 4; ++ni)
    #pragma unroll
    for (int r = 0; r < 4; ++r)
      Pw[(lg*4 + r)*72 + ((ni ^ lg)*16 + l15)] = f2b(p[ni][r]);

  short8v pa0 = *(const short8v*)(Pw + l15*72 + (((lg>>1)       ^ (l15>>2))<<4) + ((lg&1)<<3));
  short8v pa1 = *(const short8v*)(Pw + l15*72 + ((((lg>>1) + 2) ^ (l15>>2))<<4) + ((lg&1)<<3));
  #pragma unroll
  for (int fd = 0; fd < 4; ++fd) {
    const u16* vr = &Vl[(fd*16 + l15)*72 + lg*8];
    short8v v0 = *(const short8v*)(vr);
    short8v v1 = *(const short8v*)(vr + 32);
    acc[fd] = MFMA16(pa0, v0, acc[fd]);
    acc[fd] = MFMA16(pa1, v1, acc[fd]);
  }
}

template<int R>
__device__ __forceinline__ void slow_fix(
    int side, int b, int bh, int rowg0, int lane, int l15, int lg,
    const u16* __restrict__ Vt, const int* __restrict__ mask,
    float* spb, f32x4 (&acc)[4], float (&L)[4])
{
  u64 bal = __ballot(l15 == 0 && L[R] == 0.f);
  while (bal) {
    const int pos = __ffsll((unsigned long long)bal) - 1;
    bal &= bal - 1;
    const int lgi = pos >> 4;
    const int q = rowg0 + lgi*4 + R;
    float vsum = 0.f; int cnt = 0;
    const u16* vp = Vt + ((size_t)bh*64 + lane)*1024;
    for (int c = 0; c < 1024; ++c) {
      const int pm = mask[b*1024 + c];
      const bool allowed = side ? (c <= q) : (c >= q);
      const bool w = allowed ? (pm != 0) : (pm == 0);
      if (w) { cnt++; vsum += b2f(vp[c]); }
    }
    spb[lane] = vsum;           // wave-lockstep LDS roundtrip
    if (lg == lgi) {
      #pragma unroll
      for (int fd = 0; fd < 4; ++fd)
        acc[fd][R] = spb[fd*16 + l15];
      L[R] = (float)cnt;
    }
  }
}

__global__ __launch_bounds__(256) void attn_mfma(
    const u16* __restrict__ Qf, const u16* __restrict__ Kf,
    const u16* __restrict__ Vt, const int* __restrict__ mask,
    u16* __restrict__ att)
{
  __shared__ u16 Kl[64*72];
  __shared__ u16 Vl[64*72];
  __shared__ u16 Pl[4*16*72];
  __shared__ int pml[64];

  const int t = threadIdx.x;
  const int lane = t & 63, wid = t >> 6;
  const int l15 = lane & 15, lg = lane >> 4;

  // XCD swizzle: all 16 q-tiles of a bh on the same XCD
  const int x = blockIdx.x;
  const int xcd = x & 7, rest = x >> 3;
  const int qt = rest & 15, bhh = rest >> 4;
  const int bh = (bhh << 3) | xcd;
  const int b = bh / 12, h = bh - b*12;
  const int rowg0 = qt*64 + wid*16;

  short8v qa0, qa1;
  {
    const u16* Qp = Qf + ((size_t)bh*1024 + rowg0 + l15)*64 + lg*8;
    qa0 = *(const short8v*)(Qp);
    qa1 = *(const short8v*)(Qp + 32);
  }

  f32x4 accf[4], accb[4];
  float Lf[4] = {0,0,0,0}, Lb[4] = {0,0,0,0};
  #pragma unroll
  for (int i = 0; i < 4; ++i) { accf[i] = (f32x4){0,0,0,0}; accb[i] = (f32x4){0,0,0,0}; }

  const int sr = t >> 2, scq = (t & 3) * 16;
  u16* Pw = Pl + wid*1152;

  for (int kt = 0; kt < 16; ++kt) {
    __syncthreads();
    {
      const u16* ks = Kf + ((size_t)bh*1024 + kt*64 + sr)*64 + scq;
      uint4 k0 = ((const uint4*)ks)[0];
      uint4 k1 = ((const uint4*)ks)[1];
      *(uint4*)&Kl[sr*72 + scq]     = k0;
      *(uint4*)&Kl[sr*72 + scq + 8] = k1;
      const u16* vs = Vt + ((size_t)bh*64 + sr)*1024 + kt*64 + scq;
      uint4 v0 = ((const uint4*)vs)[0];
      uint4 v1 = ((const uint4*)vs)[1];
      *(uint4*)&Vl[sr*72 + scq]     = v0;
      *(uint4*)&Vl[sr*72 + scq + 8] = v1;
      if (t < 64) pml[t] = mask[b*1024 + kt*64 + t];
    }
    __syncthreads();

    f32x4 sv[4];
    #pragma unroll
    for (int ni = 0; ni < 4; ++ni) {
      const u16* kr = &Kl[(ni*16 + l15)*72 + lg*8];
      short8v b0 = *(const short8v*)(kr);
      short8v b1 = *(const short8v*)(kr + 32);
      f32x4 z = (f32x4){0,0,0,0};
      z = MFMA16(qa0, b0, z);
      z = MFMA16(qa1, b1, z);
      const int pm = pml[ni*16 + l15];
      #pragma unroll
      for (int r = 0; r < 4; ++r)
        z[r] = pm ? NEGV : z[r]*0.125f;
      sv[ni] = z;
    }

    if (kt >= qt) side_unit(sv, accf, Lf, 0, kt==qt, kt, rowg0, l15, lg, Pw, Kl==Kl?Vl:Vl);
    if (kt <= qt) side_unit(sv, accb, Lb, 1, kt==qt, kt, rowg0, l15, lg, Pw, Vl);
  }

  // reduce partial L over the 16 lanes of each row group
  #pragma unroll
  for (int s = 1; s <= 8; s <<= 1)
    #pragma unroll
    for (int r = 0; r < 4; ++r) {
      Lf[r] += __shfl_xor(Lf[r], s);
      Lb[r] += __shfl_xor(Lb[r], s);
    }

  // degenerate rows: exact recompute (rare)
  float* spb = (float*)Pw;
  slow_fix<0>(0, b, bh, rowg0, lane, l15, lg, Vt, mask, spb, accf, Lf);
  slow_fix<1>(0, b, bh, rowg0, lane, l15, lg, Vt, mask, spb, accf, Lf);
  slow_fix<2>(0, b, bh, rowg0, lane, l15, lg, Vt, mask, spb, accf, Lf);
  slow_fix<3>(0, b, bh, rowg0, lane, l15, lg, Vt, mask, spb, accf, Lf);
  slow_fix<0>(1, b, bh, rowg0, lane, l15, lg, Vt, mask, spb, accb, Lb);
  slow_fix<1>(1, b, bh, rowg0, lane, l15, lg, Vt, mask, spb, accb, Lb);
  slow_fix<2>(1, b, bh, rowg0, lane, l15, lg, Vt, mask, spb, accb, Lb);
  slow_fix<3>(1, b, bh, rowg0, lane, l15, lg, Vt, mask, spb, accb, Lb);

  float rf[4], rb[4];
  #pragma unroll
  for (int r = 0; r < 4; ++r) { rf[r] = 1.f/Lf[r]; rb[r] = 1.f/Lb[r]; }
  #pragma unroll
  for (int fd = 0; fd < 4; ++fd)
    #pragma unroll
    for (int r = 0; r < 4; ++r) {
      const float val = accf[fd][r]*rf[r] + accb[fd][r]*rb[r];
      att[((size_t)(b*1024 + rowg0 + lg*4 + r))*768 + h*64 + fd*16 + l15] = f2b(val);
    }
}

// ---------------------------------------------------------------------------
// Residual + LayerNorm: 1 block per row (768 cols, 256 threads x 3).
// ---------------------------------------------------------------------------
__global__ __launch_bounds__(256) void resid_ln(
    const float* __restrict__ qin, const float* __restrict__ proj,
    const float* __restrict__ gamma, const float* __restrict__ beta,
    float* __restrict__ out)
{
    __shared__ float red[4];
    const int row = blockIdx.x;
    const int t = threadIdx.x;
    const size_t base = (size_t)row * 768;

    float x0 = qin[base + t      ] + proj[base + t      ];
    float x1 = qin[base + t + 256] + proj[base + t + 256];
    float x2 = qin[base + t + 512] + proj[base + t + 512];

    float s = x0 + x1 + x2;
    #pragma unroll
    for (int m = 32; m >= 1; m >>= 1) s += __shfl_xor(s, m);
    if ((t & 63) == 0) red[t >> 6] = s;
    __syncthreads();
    float mu = (red[0] + red[1] + red[2] + red[3]) * (1.f / 768.f);

    float d0 = x0 - mu, d1 = x1 - mu, d2 = x2 - mu;
    float vs = d0 * d0 + d1 * d1 + d2 * d2;
    #pragma unroll
    for (int m = 32; m >= 1; m >>= 1) vs += __shfl_xor(vs, m);
    __syncthreads();
    if ((t & 63) == 0) red[t >> 6] = vs;
    __syncthreads();
    float var = (red[0] + red[1] + red[2] + red[3]) * (1.f / 768.f);
    float inv = rsqrtf(var + 1e-6f);

    out[base + t      ] = d0 * inv * gamma[t      ] + beta[t      ];
    out[base + t + 256] = d1 * inv * gamma[t + 256] + beta[t + 256];
    out[base + t + 512] = d2 * inv * gamma[t + 512] + beta[t + 512];
}

// ---------------------------------------------------------------------------
extern "C" void kernel_launch(void* const* d_in, const int* in_sizes, int n_in,
                              void* d_out, int out_size, void* d_ws, size_t ws_size,
                              hipStream_t stream)
{
    const float* q     = (const float*)d_in[0];
    const float* k     = (const float*)d_in[1];
    const float* v     = (const float*)d_in[2];
    const int*   mask  = (const int*)d_in[3];
    const float* Wq    = (const float*)d_in[4];
    const float* bq    = (const float*)d_in[5];
    const float* Wk    = (const float*)d_in[6];
    const float* bk    = (const float*)d_in[7];
    const float* Wv    = (const float*)d_in[8];
    const float* bv    = (const float*)d_in[9];
    const float* Wo    = (const float*)d_in[10];
    const float* bo    = (const float*)d_in[11];
    const float* gamma = (const float*)d_in[12];
    const float* beta  = (const float*)d_in[13];

    const size_t NE = (size_t)8 * 1024 * 768;   // 6291456
    const size_t WS = (size_t)768 * 768;
    u16* Qf  = (u16*)d_ws;          // [bh][l][64]
    u16* Kf  = Qf + NE;             // [bh][l][64]
    u16* Vt  = Kf + NE;             // [bh][d][1024]
    u16* att = Vt + NE;             // [b*l][768]
    u16* Wt  = att + NE;            // 4 x [768][768] bf16 (n-major)
    float* proj = (float*)Qf;       // aliases Qf+Kf (dead after attn)
    // ws bytes: 4*NE*2 + 4*WS*2 = 55.1 MB

    dim3 blk(256);

    wcvt<<<dim3(12,12,4), blk, 0, stream>>>(Wq, Wk, Wv, Wo, Wt);

    gemm_mfma<0,1><<<384, blk, 0, stream>>>(q, Wt,        bq, nullptr, Qf);
    gemm_mfma<0,1><<<384, blk, 0, stream>>>(k, Wt + WS,   bk, nullptr, Kf);
    gemm_mfma<0,2><<<384, blk, 0, stream>>>(v, Wt + 2*WS, bv, nullptr, Vt);

    attn_mfma<<<1536, blk, 0, stream>>>(Qf, Kf, Vt, mask, att);

    gemm_mfma<1,0><<<384, blk, 0, stream>>>(att, Wt + 3*WS, bo, proj, nullptr);

    resid_ln<<<8192, blk, 0, stream>>>(q, proj, gamma, beta, (float*)d_out);
}

// Round 6
// 352.435 us; speedup vs baseline: 2.1706x; 2.1706x over previous
//
#include <hip/hip_runtime.h>
#include <hip/hip_bf16.h>

typedef unsigned short u16;
typedef unsigned int u32;
typedef unsigned long long u64;
typedef __attribute__((ext_vector_type(8))) short short8v;
typedef __attribute__((ext_vector_type(4))) float f32x4;

#define MFMA16(a,b,c) __builtin_amdgcn_mfma_f32_16x16x32_bf16(a,b,c,0,0,0)
#define NEGV -1e9f
#define MOFF 20.0f

__device__ __forceinline__ float b2f(u16 u){ return __uint_as_float(((u32)u)<<16); }
__device__ __forceinline__ u16 f2b(float f){
  __hip_bfloat16 h = __float2bfloat16(f);   // RNE
  return __builtin_bit_cast(u16, h);
}
__device__ __forceinline__ u32 pk2(float a, float b){
  return (u32)f2b(a) | ((u32)f2b(b) << 16);
}

// ---------------------------------------------------------------------------
// Transpose+convert the 4 weight matrices: Wt[n][k] (bf16) from W[k][n] (f32).
// grid (12,12,4), block 256, 64x64 tiles.
// ---------------------------------------------------------------------------
__global__ __launch_bounds__(256) void wcvt(
    const float* __restrict__ W0, const float* __restrict__ W1,
    const float* __restrict__ W2, const float* __restrict__ W3,
    u16* __restrict__ Wt)
{
  __shared__ u16 Tl[64*72];
  const int z = blockIdx.z;
  const float* W = z==0 ? W0 : z==1 ? W1 : z==2 ? W2 : W3;
  u16* Wo = Wt + (size_t)z * 768 * 768;
  const int t = threadIdx.x;
  const int n0 = blockIdx.x*64, k0 = blockIdx.y*64;
  const int r = t>>2, cs = (t&3)*16;
  {
    const float* src = W + (size_t)(k0+r)*768 + n0 + cs;
    float4 f0 = ((const float4*)src)[0];
    float4 f1 = ((const float4*)src)[1];
    float4 f2 = ((const float4*)src)[2];
    float4 f3 = ((const float4*)src)[3];
    uint4 o0 = { pk2(f0.x,f0.y), pk2(f0.z,f0.w), pk2(f1.x,f1.y), pk2(f1.z,f1.w) };
    uint4 o1 = { pk2(f2.x,f2.y), pk2(f2.z,f2.w), pk2(f3.x,f3.y), pk2(f3.z,f3.w) };
    *(uint4*)&Tl[r*72 + cs]     = o0;
    *(uint4*)&Tl[r*72 + cs + 8] = o1;
  }
  __syncthreads();
  {
    u16 v[16];
    #pragma unroll
    for (int j = 0; j < 16; ++j) v[j] = Tl[(cs+j)*72 + r];
    uint4 o0, o1;
    u32* p0 = (u32*)&o0; u32* p1 = (u32*)&o1;
    #pragma unroll
    for (int j = 0; j < 4; ++j) p0[j] = (u32)v[2*j] | ((u32)v[2*j+1]<<16);
    #pragma unroll
    for (int j = 0; j < 4; ++j) p1[j] = (u32)v[8+2*j] | ((u32)v[8+2*j+1]<<16);
    *(uint4*)(Wo + (size_t)(n0+r)*768 + k0 + cs)     = o0;
    *(uint4*)(Wo + (size_t)(n0+r)*768 + k0 + cs + 8) = o1;
  }
}

// ---------------------------------------------------------------------------
// MFMA GEMM: C = A(8192x768) @ Wt^T + bias, Wt is [n][k] bf16.
// Tile 128x128, 4 waves (2x2), wave-tile 64x64, K-step 32.
// ---------------------------------------------------------------------------
template<int ABF16, int OMODE>
__global__ __launch_bounds__(256) void gemm_mfma(
    const void* __restrict__ Av, const u16* __restrict__ Wt,
    const float* __restrict__ bias, float* __restrict__ outF,
    u16* __restrict__ outB)
{
  __shared__ u16 Al[128*40];
  __shared__ u16 Bl[128*40];
  const int t = threadIdx.x;
  const int lane = t & 63, wid = t >> 6;
  const int l15 = lane & 15, lg = lane >> 4;
  const int wm = wid >> 1, wn = wid & 1;

  const int id = blockIdx.x;
  const int xcd = id & 7, rr = id >> 3;
  const int nb = rr % 6, mb = (rr / 6) * 8 + xcd;
  const int n0 = nb * 128, m0 = mb * 128;

  f32x4 acc[4][4];
  #pragma unroll
  for (int mi = 0; mi < 4; ++mi)
    #pragma unroll
    for (int ni = 0; ni < 4; ++ni)
      acc[mi][ni] = (f32x4){0.f,0.f,0.f,0.f};

  const int arow = t >> 1, aseg = (t & 1) * 16;

  for (int k0 = 0; k0 < 768; k0 += 32) {
    __syncthreads();
    if (ABF16) {
      const u16* A = (const u16*)Av + (size_t)(m0 + arow) * 768 + k0 + aseg;
      uint4 a0 = ((const uint4*)A)[0];
      uint4 a1 = ((const uint4*)A)[1];
      *(uint4*)&Al[arow*40 + aseg]     = a0;
      *(uint4*)&Al[arow*40 + aseg + 8] = a1;
    } else {
      const float* A = (const float*)Av + (size_t)(m0 + arow) * 768 + k0 + aseg;
      float4 f0 = ((const float4*)A)[0];
      float4 f1 = ((const float4*)A)[1];
      float4 f2 = ((const float4*)A)[2];
      float4 f3 = ((const float4*)A)[3];
      uint4 o0 = { pk2(f0.x,f0.y), pk2(f0.z,f0.w), pk2(f1.x,f1.y), pk2(f1.z,f1.w) };
      uint4 o1 = { pk2(f2.x,f2.y), pk2(f2.z,f2.w), pk2(f3.x,f3.y), pk2(f3.z,f3.w) };
      *(uint4*)&Al[arow*40 + aseg]     = o0;
      *(uint4*)&Al[arow*40 + aseg + 8] = o1;
    }
    {
      const u16* B = Wt + (size_t)(n0 + arow) * 768 + k0 + aseg;
      uint4 b0 = ((const uint4*)B)[0];
      uint4 b1 = ((const uint4*)B)[1];
      *(uint4*)&Bl[arow*40 + aseg]     = b0;
      *(uint4*)&Bl[arow*40 + aseg + 8] = b1;
    }
    __syncthreads();
    short8v af[4], bf[4];
    #pragma unroll
    for (int mi = 0; mi < 4; ++mi)
      af[mi] = *(const short8v*)&Al[(wm*64 + mi*16 + l15)*40 + lg*8];
    #pragma unroll
    for (int ni = 0; ni < 4; ++ni)
      bf[ni] = *(const short8v*)&Bl[(wn*64 + ni*16 + l15)*40 + lg*8];
    #pragma unroll
    for (int mi = 0; mi < 4; ++mi)
      #pragma unroll
      for (int ni = 0; ni < 4; ++ni)
        acc[mi][ni] = MFMA16(af[mi], bf[ni], acc[mi][ni]);
  }

  #pragma unroll
  for (int mi = 0; mi < 4; ++mi)
  #pragma unroll
  for (int ni = 0; ni < 4; ++ni) {
    const int col  = n0 + wn*64 + ni*16 + l15;
    const int row0 = m0 + wm*64 + mi*16 + lg*4;
    const float bv = bias[col];
    if (OMODE == 0) {
      #pragma unroll
      for (int r = 0; r < 4; ++r)
        outF[(size_t)(row0 + r) * 768 + col] = acc[mi][ni][r] + bv;
    } else if (OMODE == 1) {
      const int h = col >> 6, d = col & 63;
      #pragma unroll
      for (int r = 0; r < 4; ++r) {
        const int row = row0 + r;
        const int bb = row >> 10, l = row & 1023;
        outB[(((size_t)(bb*12 + h))*1024 + l)*64 + d] = f2b(acc[mi][ni][r] + bv);
      }
    } else {
      const int h = col >> 6, d = col & 63;
      const int bb = row0 >> 10, l0 = row0 & 1023;
      ushort4 pk;
      pk.x = f2b(acc[mi][ni][0] + bv);
      pk.y = f2b(acc[mi][ni][1] + bv);
      pk.z = f2b(acc[mi][ni][2] + bv);
      pk.w = f2b(acc[mi][ni][3] + bv);
      *(ushort4*)(outB + (((size_t)(bb*12 + h))*64 + d)*1024 + l0) = pk;
    }
  }
}

// ---------------------------------------------------------------------------
// Fused attention, fixed-offset softmax (M=20), directional tile skipping.
// Degenerate rows (L==0, exact) fixed by a vectorized branchless slow path
// gated by a per-block flag. Gate ballot computed on the UNIFORM path
// (round-5 bug: __ballot under lane==0 exec mask missed lg!=0 groups).
// ---------------------------------------------------------------------------
__device__ __forceinline__ void side_unit(
    const f32x4 (&sv)[4], f32x4 (&acc)[4], float (&L)[4],
    int side, bool diag, int kt, int rowg0, int l15, int lg,
    u16* Pw, const u16* Vl)
{
  float p[4][4];
  #pragma unroll
  for (int ni = 0; ni < 4; ++ni) {
    #pragma unroll
    for (int r = 0; r < 4; ++r) {
      float arg = sv[ni][r] - MOFF;
      if (diag) {
        const int colg = kt*64 + ni*16 + l15;
        const int rowg = rowg0 + lg*4 + r;
        const bool msk = side ? (colg > rowg) : (colg < rowg);
        if (msk) arg = sv[ni][r] + NEGV - MOFF;
      }
      const float pe = __expf(arg);
      p[ni][r] = pe;
      L[r] += pe;
    }
  }
  // swizzled store: col-group ^= row's lg (bank-conflict-free)
  #pragma unroll
  for (int ni = 0; ni < 4; ++ni)
    #pragma unroll
    for (int r = 0; r < 4; ++r)
      Pw[(lg*4 + r)*72 + ((ni ^ lg)*16 + l15)] = f2b(p[ni][r]);

  short8v pa0 = *(const short8v*)(Pw + l15*72 + (((lg>>1)       ^ (l15>>2))<<4) + ((lg&1)<<3));
  short8v pa1 = *(const short8v*)(Pw + l15*72 + ((((lg>>1) + 2) ^ (l15>>2))<<4) + ((lg&1)<<3));
  #pragma unroll
  for (int fd = 0; fd < 4; ++fd) {
    const u16* vr = &Vl[(fd*16 + l15)*72 + lg*8];
    short8v v0 = *(const short8v*)(vr);
    short8v v1 = *(const short8v*)(vr + 32);
    acc[fd] = MFMA16(pa0, v0, acc[fd]);
    acc[fd] = MFMA16(pa1, v1, acc[fd]);
  }
}

// Vectorized exact recompute for degenerate rows (reference semantics:
// uniform weights 1 over {allowed ? padded : non-padded}).
template<int R>
__device__ __forceinline__ void slow_fix(
    int side, int bh, int rowg0, int lane, int l15, int lg,
    const u16* __restrict__ Vt, const float* __restrict__ wfl,
    float* spb, f32x4 (&acc)[4], float (&L)[4])
{
  u64 bal = __ballot(l15 == 0 && L[R] == 0.f);
  while (bal) {
    const int pos = __ffsll((unsigned long long)bal) - 1;
    bal &= bal - 1;
    const int lgi = pos >> 4;
    const int q = rowg0 + lgi*4 + R;
    const u16* vp = Vt + ((size_t)bh*64 + lane)*1024;
    float vsum = 0.f, cnt = 0.f;
    for (int c0 = 0; c0 < 1024; c0 += 8) {
      uint4 vv = *(const uint4*)(vp + c0);
      const u16* ve = (const u16*)&vv;
      #pragma unroll
      for (int j = 0; j < 8; ++j) {
        const int c = c0 + j;
        const bool allowed = side ? (c <= q) : (c >= q);
        const float wf = wfl[c];
        const float w = allowed ? wf : 1.f - wf;
        vsum += w * b2f(ve[j]);
        cnt  += w;
      }
    }
    spb[lane] = vsum;            // wave-lockstep LDS roundtrip
    if (lg == lgi) {
      #pragma unroll
      for (int fd = 0; fd < 4; ++fd)
        acc[fd][R] = spb[fd*16 + l15];
      L[R] = cnt;
    }
  }
}

__global__ __launch_bounds__(256) void attn_mfma(
    const u16* __restrict__ Qf, const u16* __restrict__ Kf,
    const u16* __restrict__ Vt, const int* __restrict__ mask,
    u16* __restrict__ att)
{
  __shared__ u16 Kl[64*72];
  __shared__ u16 Vl[64*72];
  __shared__ u16 Pl[4*16*72];
  __shared__ int pml[64];

  const int t = threadIdx.x;
  const int lane = t & 63, wid = t >> 6;
  const int l15 = lane & 15, lg = lane >> 4;

  // XCD swizzle: all 16 q-tiles of a bh on the same XCD
  const int x = blockIdx.x;
  const int xcd = x & 7, rest = x >> 3;
  const int qt = rest & 15, bhh = rest >> 4;
  const int bh = (bhh << 3) | xcd;
  const int b = bh / 12, h = bh - b*12;
  const int rowg0 = qt*64 + wid*16;

  short8v qa0, qa1;
  {
    const u16* Qp = Qf + ((size_t)bh*1024 + rowg0 + l15)*64 + lg*8;
    qa0 = *(const short8v*)(Qp);
    qa1 = *(const short8v*)(Qp + 32);
  }

  f32x4 accf[4], accb[4];
  float Lf[4] = {0,0,0,0}, Lb[4] = {0,0,0,0};
  #pragma unroll
  for (int i = 0; i < 4; ++i) { accf[i] = (f32x4){0,0,0,0}; accb[i] = (f32x4){0,0,0,0}; }

  const int sr = t >> 2, scq = (t & 3) * 16;
  u16* Pw = Pl + wid*1152;

  for (int kt = 0; kt < 16; ++kt) {
    __syncthreads();
    {
      const u16* ks = Kf + ((size_t)bh*1024 + kt*64 + sr)*64 + scq;
      uint4 k0 = ((const uint4*)ks)[0];
      uint4 k1 = ((const uint4*)ks)[1];
      *(uint4*)&Kl[sr*72 + scq]     = k0;
      *(uint4*)&Kl[sr*72 + scq + 8] = k1;
      const u16* vs = Vt + ((size_t)bh*64 + sr)*1024 + kt*64 + scq;
      uint4 v0 = ((const uint4*)vs)[0];
      uint4 v1 = ((const uint4*)vs)[1];
      *(uint4*)&Vl[sr*72 + scq]     = v0;
      *(uint4*)&Vl[sr*72 + scq + 8] = v1;
      if (t < 64) pml[t] = mask[b*1024 + kt*64 + t];
    }
    __syncthreads();

    f32x4 sv[4];
    #pragma unroll
    for (int ni = 0; ni < 4; ++ni) {
      const u16* kr = &Kl[(ni*16 + l15)*72 + lg*8];
      short8v b0 = *(const short8v*)(kr);
      short8v b1 = *(const short8v*)(kr + 32);
      f32x4 z = (f32x4){0,0,0,0};
      z = MFMA16(qa0, b0, z);
      z = MFMA16(qa1, b1, z);
      const int pm = pml[ni*16 + l15];
      #pragma unroll
      for (int r = 0; r < 4; ++r)
        z[r] = pm ? NEGV : z[r]*0.125f;
      sv[ni] = z;
    }

    if (kt >= qt) side_unit(sv, accf, Lf, 0, kt==qt, kt, rowg0, l15, lg, Pw, Vl);
    if (kt <= qt) side_unit(sv, accb, Lb, 1, kt==qt, kt, rowg0, l15, lg, Pw, Vl);
  }

  // reduce partial L over the 16 lanes of each row group
  #pragma unroll
  for (int s = 1; s <= 8; s <<= 1)
    #pragma unroll
    for (int r = 0; r < 4; ++r) {
      Lf[r] += __shfl_xor(Lf[r], s);
      Lb[r] += __shfl_xor(Lb[r], s);
    }

  // ---- degenerate-row handling (rare; block-gated) ----
  int deg = 0;
  #pragma unroll
  for (int r = 0; r < 4; ++r)
    deg |= (Lf[r] == 0.f) | (Lb[r] == 0.f);
  const u64 degb = __ballot(deg != 0);   // UNIFORM path: all 64 lanes active
  __syncthreads();                       // Kl/Vl now dead -> reusable
  if (lane == 0) pml[wid] = (degb != 0ull) ? 1 : 0;
  __syncthreads();
  if (pml[0] | pml[1] | pml[2] | pml[3]) {
    float* wfl = (float*)Kl;             // 1024 floats in dead K tile
    #pragma unroll
    for (int j = 0; j < 4; ++j) {
      const int c = t*4 + j;
      wfl[c] = mask[b*1024 + c] ? 1.f : 0.f;
    }
    __syncthreads();
    float* spb = (float*)Pw;
    slow_fix<0>(0, bh, rowg0, lane, l15, lg, Vt, wfl, spb, accf, Lf);
    slow_fix<1>(0, bh, rowg0, lane, l15, lg, Vt, wfl, spb, accf, Lf);
    slow_fix<2>(0, bh, rowg0, lane, l15, lg, Vt, wfl, spb, accf, Lf);
    slow_fix<3>(0, bh, rowg0, lane, l15, lg, Vt, wfl, spb, accf, Lf);
    slow_fix<0>(1, bh, rowg0, lane, l15, lg, Vt, wfl, spb, accb, Lb);
    slow_fix<1>(1, bh, rowg0, lane, l15, lg, Vt, wfl, spb, accb, Lb);
    slow_fix<2>(1, bh, rowg0, lane, l15, lg, Vt, wfl, spb, accb, Lb);
    slow_fix<3>(1, bh, rowg0, lane, l15, lg, Vt, wfl, spb, accb, Lb);
  }

  float rf[4], rb[4];
  #pragma unroll
  for (int r = 0; r < 4; ++r) { rf[r] = 1.f/Lf[r]; rb[r] = 1.f/Lb[r]; }
  #pragma unroll
  for (int fd = 0; fd < 4; ++fd)
    #pragma unroll
    for (int r = 0; r < 4; ++r) {
      const float val = accf[fd][r]*rf[r] + accb[fd][r]*rb[r];
      att[((size_t)(b*1024 + rowg0 + lg*4 + r))*768 + h*64 + fd*16 + l15] = f2b(val);
    }
}

// ---------------------------------------------------------------------------
// Residual + LayerNorm: 1 block per row (768 cols, 256 threads x 3).
// ---------------------------------------------------------------------------
__global__ __launch_bounds__(256) void resid_ln(
    const float* __restrict__ qin, const float* __restrict__ proj,
    const float* __restrict__ gamma, const float* __restrict__ beta,
    float* __restrict__ out)
{
    __shared__ float red[4];
    const int row = blockIdx.x;
    const int t = threadIdx.x;
    const size_t base = (size_t)row * 768;

    float x0 = qin[base + t      ] + proj[base + t      ];
    float x1 = qin[base + t + 256] + proj[base + t + 256];
    float x2 = qin[base + t + 512] + proj[base + t + 512];

    float s = x0 + x1 + x2;
    #pragma unroll
    for (int m = 32; m >= 1; m >>= 1) s += __shfl_xor(s, m);
    if ((t & 63) == 0) red[t >> 6] = s;
    __syncthreads();
    float mu = (red[0] + red[1] + red[2] + red[3]) * (1.f / 768.f);

    float d0 = x0 - mu, d1 = x1 - mu, d2 = x2 - mu;
    float vs = d0 * d0 + d1 * d1 + d2 * d2;
    #pragma unroll
    for (int m = 32; m >= 1; m >>= 1) vs += __shfl_xor(vs, m);
    __syncthreads();
    if ((t & 63) == 0) red[t >> 6] = vs;
    __syncthreads();
    float var = (red[0] + red[1] + red[2] + red[3]) * (1.f / 768.f);
    float inv = rsqrtf(var + 1e-6f);

    out[base + t      ] = d0 * inv * gamma[t      ] + beta[t      ];
    out[base + t + 256] = d1 * inv * gamma[t + 256] + beta[t + 256];
    out[base + t + 512] = d2 * inv * gamma[t + 512] + beta[t + 512];
}

// ---------------------------------------------------------------------------
extern "C" void kernel_launch(void* const* d_in, const int* in_sizes, int n_in,
                              void* d_out, int out_size, void* d_ws, size_t ws_size,
                              hipStream_t stream)
{
    const float* q     = (const float*)d_in[0];
    const float* k     = (const float*)d_in[1];
    const float* v     = (const float*)d_in[2];
    const int*   mask  = (const int*)d_in[3];
    const float* Wq    = (const float*)d_in[4];
    const float* bq    = (const float*)d_in[5];
    const float* Wk    = (const float*)d_in[6];
    const float* bk    = (const float*)d_in[7];
    const float* Wv    = (const float*)d_in[8];
    const float* bv    = (const float*)d_in[9];
    const float* Wo    = (const float*)d_in[10];
    const float* bo    = (const float*)d_in[11];
    const float* gamma = (const float*)d_in[12];
    const float* beta  = (const float*)d_in[13];

    const size_t NE = (size_t)8 * 1024 * 768;   // 6291456
    const size_t WS = (size_t)768 * 768;
    u16* Qf  = (u16*)d_ws;          // [bh][l][64]
    u16* Kf  = Qf + NE;             // [bh][l][64]
    u16* Vt  = Kf + NE;             // [bh][d][1024]
    u16* att = Vt + NE;             // [b*l][768]
    u16* Wt  = att + NE;            // 4 x [768][768] bf16 (n-major)
    float* proj = (float*)Qf;       // aliases Qf+Kf (dead after attn)
    // ws bytes: 4*NE*2 + 4*WS*2 = 55.1 MB

    dim3 blk(256);

    wcvt<<<dim3(12,12,4), blk, 0, stream>>>(Wq, Wk, Wv, Wo, Wt);

    gemm_mfma<0,1><<<384, blk, 0, stream>>>(q, Wt,        bq, nullptr, Qf);
    gemm_mfma<0,1><<<384, blk, 0, stream>>>(k, Wt + WS,   bk, nullptr, Kf);
    gemm_mfma<0,2><<<384, blk, 0, stream>>>(v, Wt + 2*WS, bv, nullptr, Vt);

    attn_mfma<<<1536, blk, 0, stream>>>(Qf, Kf, Vt, mask, att);

    gemm_mfma<1,0><<<384, blk, 0, stream>>>(att, Wt + 3*WS, bo, proj, nullptr);

    resid_ln<<<8192, blk, 0, stream>>>(q, proj, gamma, beta, (float*)d_out);
}